// Round 22
// baseline (573.806 us; speedup 1.0000x reference)
//
#include <hip/hip_runtime.h>
#include <hip/hip_bf16.h>

// CacheFuser on MI355X (gfx950) — round 22.
// r18/r21 = 256us reproduced, spill-free. Last safe lever: amortize per-block
// cold starts. Grid 512, 2 row-tiles/block, path-major unit order
// (K,t0)(K,t1)(V,t0)(V,t1):
//  * ws (W1) loaded once per PATH, resident across both tiles;
//  * every inter-unit sharer0 stage fused into that unit's fuse-GEMM1 phase
//    (identical register profile to r18's validated phase C, NOT r19's
//    spilling phase-E pattern);
//  * naked stageDirect per CU: 4 -> 2; block generations: 4 -> 2.
// Phase graph per unit identical to r18.

typedef unsigned int  u32;
typedef unsigned short u16;
typedef __attribute__((ext_vector_type(8))) short bf16x8;   // 8 x bf16
typedef __attribute__((ext_vector_type(4))) float f32x4;

#define LL   8
#define NN   4
#define HH   256
#define RPL  8192            // rows per layer = B*S
#define BM   64              // rows per block-tile
#define ST   (BM * HH)       // 16384 u16 per tile (32 KB)

// d_ws layout: per layer 655360 u16; per matrix: k-tile-major 8192-u16 tiles,
// tile kt holds W^T[p][kt*32..kt*32+32) as [p][32] row-major.
#define LSTRIDE 655360
#define O_AKW1 0
#define O_AKW2 65536
#define O_AVW1 131072
#define O_AVW2 196608
#define O_FKW1 262144        // K=512 -> 16 tiles (0..7 recv half, 8..15 agg half)
#define O_FKW2 393216
#define O_FVW1 458752
#define O_FVW2 589824
// total 5242880 u16 = 10485760 B in d_ws

__device__ __forceinline__ u16 f2bf(float f) {
  return __builtin_bit_cast(u16, __float2bfloat16(f));   // RNE, pairs to v_cvt_pk_bf16_f32
}
__device__ __forceinline__ float bf2f(u16 b) {
  u32 u = ((u32)b) << 16;
  return __builtin_bit_cast(float, u);
}
__device__ __forceinline__ float4 ldf4(const float* p) { return *(const float4*)p; }

// ---------------- prep: W[k][p] f32 -> k-tile-major bf16 W^T tiles -----------
__global__ __launch_bounds__(256) void prep_wt_k(
    const float* __restrict__ s0, const float* __restrict__ s1,
    const float* __restrict__ s2, const float* __restrict__ s3,
    const float* __restrict__ s4, const float* __restrict__ s5,
    const float* __restrict__ s6, const float* __restrict__ s7,
    u16* __restrict__ wt)
{
  __shared__ float tile[32][33];
  const int mat = blockIdx.z, l = blockIdx.y, t = blockIdx.x;
  const float* src; int off, K;
  switch (mat) {
    case 0: src = s0; off = O_AKW1; K = 256; break;
    case 1: src = s1; off = O_AKW2; K = 256; break;
    case 2: src = s2; off = O_AVW1; K = 256; break;
    case 3: src = s3; off = O_AVW2; K = 256; break;
    case 4: src = s4; off = O_FKW1; K = 512; break;
    case 5: src = s5; off = O_FKW2; K = 256; break;
    case 6: src = s6; off = O_FVW1; K = 512; break;
    default: src = s7; off = O_FVW2; K = 256; break;
  }
  const int ntk = K >> 5;
  if (t >= ntk * 8) return;                 // 8 p-tiles of 32
  const int tk = t % ntk, tp = t / ntk;
  src += (size_t)l * K * HH;
  u16* dst = wt + (size_t)l * LSTRIDE + off;
  #pragma unroll
  for (int i = 0; i < 4; ++i) {
    int idx = threadIdx.x + i * 256;
    int r = idx >> 5, c = idx & 31;        // r = k-local, c = p-local
    tile[r][c] = src[(size_t)(tk * 32 + r) * HH + tp * 32 + c];
  }
  __syncthreads();
  const int pl = threadIdx.x >> 3, kq = threadIdx.x & 7;
  const int p = tp * 32 + pl;
  ushort4 o;
  o.x = f2bf(tile[kq * 4 + 0][pl]);
  o.y = f2bf(tile[kq * 4 + 1][pl]);
  o.z = f2bf(tile[kq * 4 + 2][pl]);
  o.w = f2bf(tile[kq * 4 + 3][pl]);
  *(ushort4*)(dst + (size_t)tk * 8192 + p * 32 + kq * 4) = o;
}

// ---------------- main kernel helpers ---------------------------------------
__device__ __forceinline__ void zero24(f32x4 (&a)[2][4]) {
  f32x4 z = {0.f, 0.f, 0.f, 0.f};
  #pragma unroll
  for (int i = 0; i < 2; ++i)
    #pragma unroll
    for (int j = 0; j < 4; ++j) a[i][j] = z;
}

__device__ __forceinline__ void stWrite(u16* dst, const float4& v, int idx) {
  int q = idx >> 6, c = (idx & 63) * 4;
  ushort4 o;
  o.x = f2bf(v.x); o.y = f2bf(v.y);
  o.z = f2bf(v.z); o.w = f2bf(v.w);
  *(ushort4*)(dst + q * HH + (c ^ ((q & 7) << 3))) = o;
}

__device__ __forceinline__ void loadWS(bf16x8 (&ws)[16], const u16* W1, int w, int lr, int g) {
  const u16* wl = W1 + (w * 32 + lr) * 32 + g * 8;
  #pragma unroll
  for (int kt = 0; kt < 8; ++kt)
    #pragma unroll
    for (int fp = 0; fp < 2; ++fp)
      ws[kt * 2 + fp] = *(const bf16x8*)(wl + kt * 8192 + fp * 512);
}

// GEMM with register-resident W slice. STG: load whole [64][256] f32 tile
// into slot[8] at entry, PIN with sched_barrier(0) so LLVM cannot sink the
// loads, write to LDS (swizzled bf16) after the 64-MFMA loop (~2500cy lead).
template<bool STG>
__device__ __forceinline__ void gemm8R(
    f32x4 (&acc)[2][4], const bf16x8 (&ws)[16], const u16* __restrict__ act,
    const float* __restrict__ src, u16* __restrict__ dst,
    int tid, int lr, int g)
{
  float4 slot[8];
  if (STG) {
    #pragma unroll
    for (int c = 0; c < 8; ++c)
      slot[c] = ldf4(src + (size_t)(c * 512 + tid) * 4);
    __builtin_amdgcn_sched_barrier(0);     // pin: loads may not sink past here
  }
  #pragma unroll
  for (int kt = 0; kt < 8; ++kt) {
    bf16x8 b[4];
    #pragma unroll
    for (int fq = 0; fq < 4; ++fq) {
      int q = fq * 16 + lr;
      int k = (kt * 32 + g * 8) ^ ((q & 7) << 3);
      b[fq] = *(const bf16x8*)(act + q * HH + k);
    }
    #pragma unroll
    for (int fp = 0; fp < 2; ++fp)
      #pragma unroll
      for (int fq = 0; fq < 4; ++fq)
        acc[fp][fq] = __builtin_amdgcn_mfma_f32_16x16x32_bf16(ws[kt * 2 + fp], b[fq], acc[fp][fq], 0, 0, 0);
  }
  if (STG) {
    __builtin_amdgcn_sched_barrier(0);     // writes stay after the MFMA loop
    #pragma unroll
    for (int c = 0; c < 8; ++c)
      stWrite(dst, slot[c], c * 512 + tid);
  }
}

// GEMM streaming W from L2 (4-deep a-ring); optional pinned staging as above.
template<bool STG>
__device__ __forceinline__ void gemm8S(
    f32x4 (&acc)[2][4], const u16* __restrict__ wtile, const u16* __restrict__ act,
    const float* __restrict__ src, u16* __restrict__ dst,
    int tid, int w, int lr, int g)
{
  const u16* wl = wtile + (w * 32 + lr) * 32 + g * 8;   // +fp*512, +kt*8192
  bf16x8 a[4][2];
  #pragma unroll
  for (int c = 0; c < 3; ++c)
    #pragma unroll
    for (int fp = 0; fp < 2; ++fp)
      a[c][fp] = *(const bf16x8*)(wl + c * 8192 + fp * 512);
  __builtin_amdgcn_sched_barrier(0x38F);   // a-loads ahead of slot loads (FIFO)
  float4 slot[8];
  if (STG) {
    #pragma unroll
    for (int c = 0; c < 8; ++c)
      slot[c] = ldf4(src + (size_t)(c * 512 + tid) * 4);
    __builtin_amdgcn_sched_barrier(0);     // pin
  }
  #pragma unroll
  for (int kt = 0; kt < 8; ++kt) {
    const int cur = kt & 3;
    if (kt < 5) {
      #pragma unroll
      for (int fp = 0; fp < 2; ++fp)
        a[(kt + 3) & 3][fp] = *(const bf16x8*)(wl + (kt + 3) * 8192 + fp * 512);
    }
    bf16x8 b[4];
    #pragma unroll
    for (int fq = 0; fq < 4; ++fq) {
      int q = fq * 16 + lr;
      int k = (kt * 32 + g * 8) ^ ((q & 7) << 3);
      b[fq] = *(const bf16x8*)(act + q * HH + k);
    }
    #pragma unroll
    for (int fp = 0; fp < 2; ++fp)
      #pragma unroll
      for (int fq = 0; fq < 4; ++fq)
        acc[fp][fq] = __builtin_amdgcn_mfma_f32_16x16x32_bf16(a[cur][fp], b[fq], acc[fp][fq], 0, 0, 0);
  }
  if (STG) {
    __builtin_amdgcn_sched_barrier(0);
    #pragma unroll
    for (int c = 0; c < 8; ++c)
      stWrite(dst, slot[c], c * 512 + tid);
  }
}

// One-shot staging: [64][256] f32 -> swizzled bf16 LDS.
__device__ __forceinline__ void stageDirect(u16* dst, const float* __restrict__ src, int tid) {
  #pragma unroll
  for (int i = 0; i < 8; ++i) {
    float4 v = ldf4(src + (size_t)(i * 512 + tid) * 4);
    stWrite(dst, v, i * 512 + tid);
  }
}

// HS (bf16, owner-exclusive RMW): HS[q][p] (+)= sn * relu(acc + b1)
template<bool INIT>
__device__ __forceinline__ void hsUpd(
    u16* HS, f32x4 (&acc)[2][4], const float* __restrict__ b1,
    float sn, int w, int lr, int g)
{
  #pragma unroll
  for (int fp = 0; fp < 2; ++fp) {
    int p0 = w * 32 + fp * 16 + g * 4;
    float4 bv = *(const float4*)(b1 + p0);
    #pragma unroll
    for (int fq = 0; fq < 4; ++fq) {
      int q = fq * 16 + lr;
      u16* addr = HS + q * HH + (p0 ^ ((q & 7) << 3));
      float v0 = sn * fmaxf(acc[fp][fq][0] + bv.x, 0.f);
      float v1 = sn * fmaxf(acc[fp][fq][1] + bv.y, 0.f);
      float v2 = sn * fmaxf(acc[fp][fq][2] + bv.z, 0.f);
      float v3 = sn * fmaxf(acc[fp][fq][3] + bv.w, 0.f);
      if (!INIT) {
        ushort4 old = *(ushort4*)addr;
        v0 += bf2f(old.x); v1 += bf2f(old.y);
        v2 += bf2f(old.z); v3 += bf2f(old.w);
      }
      ushort4 o;
      o.x = f2bf(v0); o.y = f2bf(v1);
      o.z = f2bf(v2); o.w = f2bf(v3);
      *(ushort4*)addr = o;
    }
  }
}

// acc -> swizzled bf16 LDS: v = [relu?](acc + bscale*bias)
__device__ __forceinline__ void epiLds(
    u16* buf, f32x4 (&acc)[2][4], const float* __restrict__ bias,
    float bscale, bool doRelu, int w, int lr, int g)
{
  #pragma unroll
  for (int fp = 0; fp < 2; ++fp) {
    int p0 = w * 32 + fp * 16 + g * 4;
    float4 bv = *(const float4*)(bias + p0);
    #pragma unroll
    for (int fq = 0; fq < 4; ++fq) {
      int q = fq * 16 + lr;
      float v0 = acc[fp][fq][0] + bscale * bv.x;
      float v1 = acc[fp][fq][1] + bscale * bv.y;
      float v2 = acc[fp][fq][2] + bscale * bv.z;
      float v3 = acc[fp][fq][3] + bscale * bv.w;
      if (doRelu) {
        v0 = fmaxf(v0, 0.f); v1 = fmaxf(v1, 0.f);
        v2 = fmaxf(v2, 0.f); v3 = fmaxf(v3, 0.f);
      }
      ushort4 o;
      o.x = f2bf(v0); o.y = f2bf(v1);
      o.z = f2bf(v2); o.w = f2bf(v3);
      *(ushort4*)(buf + q * HH + (p0 ^ ((q & 7) << 3))) = o;
    }
  }
}

// out = recv + gate*(acc + bias)
__device__ __forceinline__ void epiOut(
    f32x4 (&acc)[2][4], const float* __restrict__ bias,
    const float* __restrict__ recv, float* __restrict__ outp,
    float gate, int w, int lr, int g)
{
  #pragma unroll
  for (int fp = 0; fp < 2; ++fp) {
    int p0 = w * 32 + fp * 16 + g * 4;
    float4 bv = *(const float4*)(bias + p0);
    #pragma unroll
    for (int fq = 0; fq < 4; ++fq) {
      int q = fq * 16 + lr;
      float4 rv = *(const float4*)(recv + (size_t)q * HH + p0);
      float4 ov;
      ov.x = rv.x + gate * (acc[fp][fq][0] + bv.x);
      ov.y = rv.y + gate * (acc[fp][fq][1] + bv.y);
      ov.z = rv.z + gate * (acc[fp][fq][2] + bv.z);
      ov.w = rv.w + gate * (acc[fp][fq][3] + bv.w);
      *(float4*)(outp + (size_t)q * HH + p0) = ov;
    }
  }
}

__global__ __launch_bounds__(512) void CacheFuser_73873437491748_kernel(
    const float* __restrict__ recv_k, const float* __restrict__ recv_v,
    const float* __restrict__ shar_k, const float* __restrict__ shar_v,
    const float* __restrict__ ew, const float* __restrict__ alpha,
    const float* __restrict__ ak_b1, const float* __restrict__ ak_b2,
    const float* __restrict__ av_b1, const float* __restrict__ av_b2,
    const float* __restrict__ fk_b1, const float* __restrict__ fk_b2,
    const float* __restrict__ fv_b1, const float* __restrict__ fv_b2,
    const u16* __restrict__ wt, float* __restrict__ out)
{
  __shared__ u16 XA[ST];        // 32 KB input ping (swizzled bf16)
  __shared__ u16 XB[ST];        // 32 KB input pong
  __shared__ u16 HS[ST];        // 32 KB bf16 hidden-sum; later fuse-hidden
  __shared__ u16 FB[ST];        // 32 KB agg tile
  // total 128 KB -> 1 block/CU, 2 waves/SIMD -> 256-reg budget

  const int bid = blockIdx.x;                   // 512 blocks
  const int l = bid & 7, t = bid >> 3;          // layer <-> XCD; t in [0,64)
  const int tid = threadIdx.x;
  const int w = tid >> 6, lane = tid & 63, lr = lane & 15, g = lane >> 4;

  const u16* lw = wt + (size_t)l * LSTRIDE;
  const float gate = 1.f / (1.f + __expf(-2.f * alpha[l]));
  const float* ewl = ew + l * NN;

  // row offsets for the two tiles this block owns
  const size_t rowT[2] = { (size_t)(t * 2) * BM, (size_t)(t * 2 + 1) * BM };

  stageDirect(XA, shar_k + ((size_t)l * NN * RPL + rowT[0]) * HH, tid);  // (K,t0) sharer0

  bf16x8 ws[16];
  int cur = 0;

  #pragma unroll 1
  for (int path = 0; path < 2; ++path) {
    const u16* W1  = lw + (path ? O_AVW1 : O_AKW1);
    const u16* W2  = lw + (path ? O_AVW2 : O_AKW2);
    const u16* FW1 = lw + (path ? O_FVW1 : O_FKW1);
    const u16* FW2 = lw + (path ? O_FVW2 : O_FKW2);
    const float* b1  = (path ? av_b1 : ak_b1) + l * HH;
    const float* b2  = (path ? av_b2 : ak_b2) + l * HH;
    const float* fb1 = (path ? fv_b1 : fk_b1) + l * HH;
    const float* fb2 = (path ? fv_b2 : fk_b2) + l * HH;
    const float* recvBase = path ? recv_v : recv_k;
    const float* sharBase = path ? shar_v : shar_k;

    loadWS(ws, W1, w, lr, g);                  // resident across BOTH tiles

    #pragma unroll 1
    for (int tt = 0; tt < 2; ++tt) {
      const int u = path * 2 + tt;             // unit index 0..3
      const size_t row0 = rowT[tt];
      const float* recvB = recvBase + ((size_t)l * RPL + row0) * HH;
      const float* sharB = sharBase + ((size_t)l * NN * RPL + row0) * HH;
      float* outp = out + ((size_t)(path * LL + l) * RPL + row0) * HH;

      // next unit's sharer0 global pointer (u==3: none)
      const int np = (u + 1) >> 1, ntt = (u + 1) & 1;
      const float* nextShar0 = (np ? shar_v : shar_k) +
          ((size_t)l * NN * RPL + rowT[ntt]) * HH;

      float sS = 0.f;
      #pragma unroll 1
      for (int n = 0; n < NN; ++n) {
        float sn = ewl[n] * 0.25f; sS += sn;
        __syncthreads();                       // input n ready in cur buffer
        u16* XC = cur ? XB : XA;
        u16* XO = cur ? XA : XB;
        const float* nsrc = (n < 3) ? sharB + (size_t)(n + 1) * RPL * HH : recvB;
        f32x4 h[2][4]; zero24(h);
        gemm8R<true>(h, ws, XC, nsrc, XO, tid, lr, g);
        if (n == 0) hsUpd<true >(HS, h, b1, sn, w, lr, g);
        else        hsUpd<false>(HS, h, b1, sn, w, lr, g);
        cur ^= 1;
      }
      u16* XR = cur ? XB : XA;                 // recv tile
      u16* XD = cur ? XA : XB;                 // dead buffer (stage target)
      __syncthreads();                         // HS complete; recv staged
      f32x4 agg[2][4]; zero24(agg);
      gemm8S<false>(agg, W2, HS, nullptr, nullptr, tid, w, lr, g);
      epiLds(FB, agg, b2, sS, false, w, lr, g);     // FB = agg + sS*b2
      __syncthreads();                         // FB ready; HS reads done
      f32x4 h2[2][4]; zero24(h2);
      if (u < 3) {
        // fuse GEMM1 (recv half) while staging next unit's sharer0 -> XD
        gemm8S<true>(h2, FW1, XR, nextShar0, XD, tid, w, lr, g);
      } else {
        gemm8S<false>(h2, FW1, XR, nullptr, nullptr, tid, w, lr, g);
      }
      gemm8S<false>(h2, FW1 + 8 * 8192, FB, nullptr, nullptr, tid, w, lr, g);
      epiLds(HS, h2, fb1, 1.f, true, w, lr, g);     // HS = fuse hidden
      __syncthreads();                         // fuse hidden ready
      f32x4 dd[2][4]; zero24(dd);
      gemm8S<false>(dd, FW2, HS, nullptr, nullptr, tid, w, lr, g);
      epiOut(dd, fb2, recvB, outp, gate, w, lr, g);
      cur ^= 1;                                // next unit's sharer0 sits in XD
    }
  }
}

extern "C" void kernel_launch(void* const* d_in, const int* in_sizes, int n_in,
                              void* d_out, int out_size, void* d_ws, size_t ws_size,
                              hipStream_t stream)
{
  const float* recv_k = (const float*)d_in[0];
  const float* recv_v = (const float*)d_in[1];
  const float* shar_k = (const float*)d_in[2];
  const float* shar_v = (const float*)d_in[3];
  const float* ew     = (const float*)d_in[4];
  const float* alpha  = (const float*)d_in[5];
  const float* ak_w1 = (const float*)d_in[6];  const float* ak_b1 = (const float*)d_in[7];
  const float* ak_w2 = (const float*)d_in[8];  const float* ak_b2 = (const float*)d_in[9];
  const float* av_w1 = (const float*)d_in[10]; const float* av_b1 = (const float*)d_in[11];
  const float* av_w2 = (const float*)d_in[12]; const float* av_b2 = (const float*)d_in[13];
  const float* fk_w1 = (const float*)d_in[14]; const float* fk_b1 = (const float*)d_in[15];
  const float* fk_w2 = (const float*)d_in[16]; const float* fk_b2 = (const float*)d_in[17];
  const float* fv_w1 = (const float*)d_in[18]; const float* fv_b1 = (const float*)d_in[19];
  const float* fv_w2 = (const float*)d_in[20]; const float* fv_b2 = (const float*)d_in[21];
  u16* wtw = (u16*)d_ws;          // 10485760 B
  float* outp = (float*)d_out;

  prep_wt_k<<<dim3(128, 8, 8), dim3(256), 0, stream>>>(
      ak_w1, ak_w2, av_w1, av_w2, fk_w1, fk_w2, fv_w1, fv_w2, wtw);

  CacheFuser_73873437491748_kernel<<<dim3(512), dim3(512), 0, stream>>>(
      recv_k, recv_v, shar_k, shar_v, ew, alpha,
      ak_b1, ak_b2, av_b1, av_b2, fk_b1, fk_b2, fv_b1, fv_b2, wtw, outp);
}

// Round 23
// 255.584 us; speedup vs baseline: 2.2451x; 2.2451x over previous
//
#include <hip/hip_runtime.h>
#include <hip/hip_bf16.h>

// CacheFuser on MI355X (gfx950) — round 23 (= r18/r21, the validated best: 256us).
// Final configuration after 22 rounds. r19/r20/r22 each proved that raising
// per-phase live registers beyond this profile (phase merges, cross-phase
// ws residency) spills and costs 25-300us vs ~10us of ramp savings.
// Structure:
//  * BM=64, grid 1024 (layer<->XCD affinity), 1 block/CU, 2 waves/SIMD
//    (256-reg unified budget), LDS 4x32KB.
//  * Weights pre-transposed+cast to bf16 k-tile-major in d_ws (prep kernel).
//  * W1 register-resident align GEMMs (W read once/path, no VMEM in k-loop);
//    ws dies after the align loop -- that dead window funds phases C-E.
//  * All activation staging fused into GEMM phases: slot[8] loaded at entry,
//    pinned with sched_barrier(0), written to swizzled bf16 LDS after the
//    64-MFMA loop (~2500cy lead covers HBM latency).
//  * Hidden-sum accumulated by owner-exclusive bf16 RMW in LDS (no second
//    register accumulator -- the single-accumulator rule from r1-r9).
//  * cvt_pk bf16 epilogues (__float2bfloat16 pairs to v_cvt_pk_bf16_f32).

typedef unsigned int  u32;
typedef unsigned short u16;
typedef __attribute__((ext_vector_type(8))) short bf16x8;   // 8 x bf16
typedef __attribute__((ext_vector_type(4))) float f32x4;

#define LL   8
#define NN   4
#define HH   256
#define RPL  8192            // rows per layer = B*S
#define BM   64              // rows per block
#define ST   (BM * HH)       // 16384 u16 per tile (32 KB)

// d_ws layout: per layer 655360 u16; per matrix: k-tile-major 8192-u16 tiles,
// tile kt holds W^T[p][kt*32..kt*32+32) as [p][32] row-major.
#define LSTRIDE 655360
#define O_AKW1 0
#define O_AKW2 65536
#define O_AVW1 131072
#define O_AVW2 196608
#define O_FKW1 262144        // K=512 -> 16 tiles (0..7 recv half, 8..15 agg half)
#define O_FKW2 393216
#define O_FVW1 458752
#define O_FVW2 589824
// total 5242880 u16 = 10485760 B in d_ws

__device__ __forceinline__ u16 f2bf(float f) {
  return __builtin_bit_cast(u16, __float2bfloat16(f));   // RNE, pairs to v_cvt_pk_bf16_f32
}
__device__ __forceinline__ float bf2f(u16 b) {
  u32 u = ((u32)b) << 16;
  return __builtin_bit_cast(float, u);
}
__device__ __forceinline__ float4 ldf4(const float* p) { return *(const float4*)p; }

// ---------------- prep: W[k][p] f32 -> k-tile-major bf16 W^T tiles -----------
__global__ __launch_bounds__(256) void prep_wt_k(
    const float* __restrict__ s0, const float* __restrict__ s1,
    const float* __restrict__ s2, const float* __restrict__ s3,
    const float* __restrict__ s4, const float* __restrict__ s5,
    const float* __restrict__ s6, const float* __restrict__ s7,
    u16* __restrict__ wt)
{
  __shared__ float tile[32][33];
  const int mat = blockIdx.z, l = blockIdx.y, t = blockIdx.x;
  const float* src; int off, K;
  switch (mat) {
    case 0: src = s0; off = O_AKW1; K = 256; break;
    case 1: src = s1; off = O_AKW2; K = 256; break;
    case 2: src = s2; off = O_AVW1; K = 256; break;
    case 3: src = s3; off = O_AVW2; K = 256; break;
    case 4: src = s4; off = O_FKW1; K = 512; break;
    case 5: src = s5; off = O_FKW2; K = 256; break;
    case 6: src = s6; off = O_FVW1; K = 512; break;
    default: src = s7; off = O_FVW2; K = 256; break;
  }
  const int ntk = K >> 5;
  if (t >= ntk * 8) return;                 // 8 p-tiles of 32
  const int tk = t % ntk, tp = t / ntk;
  src += (size_t)l * K * HH;
  u16* dst = wt + (size_t)l * LSTRIDE + off;
  #pragma unroll
  for (int i = 0; i < 4; ++i) {
    int idx = threadIdx.x + i * 256;
    int r = idx >> 5, c = idx & 31;        // r = k-local, c = p-local
    tile[r][c] = src[(size_t)(tk * 32 + r) * HH + tp * 32 + c];
  }
  __syncthreads();
  const int pl = threadIdx.x >> 3, kq = threadIdx.x & 7;
  const int p = tp * 32 + pl;
  ushort4 o;
  o.x = f2bf(tile[kq * 4 + 0][pl]);
  o.y = f2bf(tile[kq * 4 + 1][pl]);
  o.z = f2bf(tile[kq * 4 + 2][pl]);
  o.w = f2bf(tile[kq * 4 + 3][pl]);
  *(ushort4*)(dst + (size_t)tk * 8192 + p * 32 + kq * 4) = o;
}

// ---------------- main kernel helpers ---------------------------------------
__device__ __forceinline__ void zero24(f32x4 (&a)[2][4]) {
  f32x4 z = {0.f, 0.f, 0.f, 0.f};
  #pragma unroll
  for (int i = 0; i < 2; ++i)
    #pragma unroll
    for (int j = 0; j < 4; ++j) a[i][j] = z;
}

__device__ __forceinline__ void stWrite(u16* dst, const float4& v, int idx) {
  int q = idx >> 6, c = (idx & 63) * 4;
  ushort4 o;
  o.x = f2bf(v.x); o.y = f2bf(v.y);
  o.z = f2bf(v.z); o.w = f2bf(v.w);
  *(ushort4*)(dst + q * HH + (c ^ ((q & 7) << 3))) = o;
}

// GEMM with register-resident W slice. STG: load whole [64][256] f32 tile
// into slot[8] at entry, PIN with sched_barrier(0) so LLVM cannot sink the
// loads, write to LDS (swizzled bf16) after the 64-MFMA loop (~2500cy lead).
template<bool STG>
__device__ __forceinline__ void gemm8R(
    f32x4 (&acc)[2][4], const bf16x8 (&ws)[16], const u16* __restrict__ act,
    const float* __restrict__ src, u16* __restrict__ dst,
    int tid, int lr, int g)
{
  float4 slot[8];
  if (STG) {
    #pragma unroll
    for (int c = 0; c < 8; ++c)
      slot[c] = ldf4(src + (size_t)(c * 512 + tid) * 4);
    __builtin_amdgcn_sched_barrier(0);     // pin: loads may not sink past here
  }
  #pragma unroll
  for (int kt = 0; kt < 8; ++kt) {
    bf16x8 b[4];
    #pragma unroll
    for (int fq = 0; fq < 4; ++fq) {
      int q = fq * 16 + lr;
      int k = (kt * 32 + g * 8) ^ ((q & 7) << 3);
      b[fq] = *(const bf16x8*)(act + q * HH + k);
    }
    #pragma unroll
    for (int fp = 0; fp < 2; ++fp)
      #pragma unroll
      for (int fq = 0; fq < 4; ++fq)
        acc[fp][fq] = __builtin_amdgcn_mfma_f32_16x16x32_bf16(ws[kt * 2 + fp], b[fq], acc[fp][fq], 0, 0, 0);
  }
  if (STG) {
    __builtin_amdgcn_sched_barrier(0);     // writes stay after the MFMA loop
    #pragma unroll
    for (int c = 0; c < 8; ++c)
      stWrite(dst, slot[c], c * 512 + tid);
  }
}

// GEMM streaming W from L2 (4-deep a-ring); optional pinned staging as above.
template<bool STG>
__device__ __forceinline__ void gemm8S(
    f32x4 (&acc)[2][4], const u16* __restrict__ wtile, const u16* __restrict__ act,
    const float* __restrict__ src, u16* __restrict__ dst,
    int tid, int w, int lr, int g)
{
  const u16* wl = wtile + (w * 32 + lr) * 32 + g * 8;   // +fp*512, +kt*8192
  bf16x8 a[4][2];
  #pragma unroll
  for (int c = 0; c < 3; ++c)
    #pragma unroll
    for (int fp = 0; fp < 2; ++fp)
      a[c][fp] = *(const bf16x8*)(wl + c * 8192 + fp * 512);
  __builtin_amdgcn_sched_barrier(0x38F);   // a-loads ahead of slot loads (FIFO)
  float4 slot[8];
  if (STG) {
    #pragma unroll
    for (int c = 0; c < 8; ++c)
      slot[c] = ldf4(src + (size_t)(c * 512 + tid) * 4);
    __builtin_amdgcn_sched_barrier(0);     // pin
  }
  #pragma unroll
  for (int kt = 0; kt < 8; ++kt) {
    const int cur = kt & 3;
    if (kt < 5) {
      #pragma unroll
      for (int fp = 0; fp < 2; ++fp)
        a[(kt + 3) & 3][fp] = *(const bf16x8*)(wl + (kt + 3) * 8192 + fp * 512);
    }
    bf16x8 b[4];
    #pragma unroll
    for (int fq = 0; fq < 4; ++fq) {
      int q = fq * 16 + lr;
      int k = (kt * 32 + g * 8) ^ ((q & 7) << 3);
      b[fq] = *(const bf16x8*)(act + q * HH + k);
    }
    #pragma unroll
    for (int fp = 0; fp < 2; ++fp)
      #pragma unroll
      for (int fq = 0; fq < 4; ++fq)
        acc[fp][fq] = __builtin_amdgcn_mfma_f32_16x16x32_bf16(a[cur][fp], b[fq], acc[fp][fq], 0, 0, 0);
  }
  if (STG) {
    __builtin_amdgcn_sched_barrier(0);
    #pragma unroll
    for (int c = 0; c < 8; ++c)
      stWrite(dst, slot[c], c * 512 + tid);
  }
}

// One-shot staging: [64][256] f32 -> swizzled bf16 LDS.
__device__ __forceinline__ void stageDirect(u16* dst, const float* __restrict__ src, int tid) {
  #pragma unroll
  for (int i = 0; i < 8; ++i) {
    float4 v = ldf4(src + (size_t)(i * 512 + tid) * 4);
    stWrite(dst, v, i * 512 + tid);
  }
}

// HS (bf16, owner-exclusive RMW): HS[q][p] (+)= sn * relu(acc + b1)
template<bool INIT>
__device__ __forceinline__ void hsUpd(
    u16* HS, f32x4 (&acc)[2][4], const float* __restrict__ b1,
    float sn, int w, int lr, int g)
{
  #pragma unroll
  for (int fp = 0; fp < 2; ++fp) {
    int p0 = w * 32 + fp * 16 + g * 4;
    float4 bv = *(const float4*)(b1 + p0);
    #pragma unroll
    for (int fq = 0; fq < 4; ++fq) {
      int q = fq * 16 + lr;
      u16* addr = HS + q * HH + (p0 ^ ((q & 7) << 3));
      float v0 = sn * fmaxf(acc[fp][fq][0] + bv.x, 0.f);
      float v1 = sn * fmaxf(acc[fp][fq][1] + bv.y, 0.f);
      float v2 = sn * fmaxf(acc[fp][fq][2] + bv.z, 0.f);
      float v3 = sn * fmaxf(acc[fp][fq][3] + bv.w, 0.f);
      if (!INIT) {
        ushort4 old = *(ushort4*)addr;
        v0 += bf2f(old.x); v1 += bf2f(old.y);
        v2 += bf2f(old.z); v3 += bf2f(old.w);
      }
      ushort4 o;
      o.x = f2bf(v0); o.y = f2bf(v1);
      o.z = f2bf(v2); o.w = f2bf(v3);
      *(ushort4*)addr = o;
    }
  }
}

// acc -> swizzled bf16 LDS: v = [relu?](acc + bscale*bias)
__device__ __forceinline__ void epiLds(
    u16* buf, f32x4 (&acc)[2][4], const float* __restrict__ bias,
    float bscale, bool doRelu, int w, int lr, int g)
{
  #pragma unroll
  for (int fp = 0; fp < 2; ++fp) {
    int p0 = w * 32 + fp * 16 + g * 4;
    float4 bv = *(const float4*)(bias + p0);
    #pragma unroll
    for (int fq = 0; fq < 4; ++fq) {
      int q = fq * 16 + lr;
      float v0 = acc[fp][fq][0] + bscale * bv.x;
      float v1 = acc[fp][fq][1] + bscale * bv.y;
      float v2 = acc[fp][fq][2] + bscale * bv.z;
      float v3 = acc[fp][fq][3] + bscale * bv.w;
      if (doRelu) {
        v0 = fmaxf(v0, 0.f); v1 = fmaxf(v1, 0.f);
        v2 = fmaxf(v2, 0.f); v3 = fmaxf(v3, 0.f);
      }
      ushort4 o;
      o.x = f2bf(v0); o.y = f2bf(v1);
      o.z = f2bf(v2); o.w = f2bf(v3);
      *(ushort4*)(buf + q * HH + (p0 ^ ((q & 7) << 3))) = o;
    }
  }
}

// out = recv + gate*(acc + bias)
__device__ __forceinline__ void epiOut(
    f32x4 (&acc)[2][4], const float* __restrict__ bias,
    const float* __restrict__ recv, float* __restrict__ outp,
    float gate, int w, int lr, int g)
{
  #pragma unroll
  for (int fp = 0; fp < 2; ++fp) {
    int p0 = w * 32 + fp * 16 + g * 4;
    float4 bv = *(const float4*)(bias + p0);
    #pragma unroll
    for (int fq = 0; fq < 4; ++fq) {
      int q = fq * 16 + lr;
      float4 rv = *(const float4*)(recv + (size_t)q * HH + p0);
      float4 ov;
      ov.x = rv.x + gate * (acc[fp][fq][0] + bv.x);
      ov.y = rv.y + gate * (acc[fp][fq][1] + bv.y);
      ov.z = rv.z + gate * (acc[fp][fq][2] + bv.z);
      ov.w = rv.w + gate * (acc[fp][fq][3] + bv.w);
      *(float4*)(outp + (size_t)q * HH + p0) = ov;
    }
  }
}

__global__ __launch_bounds__(512) void CacheFuser_73873437491748_kernel(
    const float* __restrict__ recv_k, const float* __restrict__ recv_v,
    const float* __restrict__ shar_k, const float* __restrict__ shar_v,
    const float* __restrict__ ew, const float* __restrict__ alpha,
    const float* __restrict__ ak_b1, const float* __restrict__ ak_b2,
    const float* __restrict__ av_b1, const float* __restrict__ av_b2,
    const float* __restrict__ fk_b1, const float* __restrict__ fk_b2,
    const float* __restrict__ fv_b1, const float* __restrict__ fv_b2,
    const u16* __restrict__ wt, float* __restrict__ out)
{
  __shared__ u16 XA[ST];        // 32 KB input ping (swizzled bf16)
  __shared__ u16 XB[ST];        // 32 KB input pong
  __shared__ u16 HS[ST];        // 32 KB bf16 hidden-sum; later fuse-hidden
  __shared__ u16 FB[ST];        // 32 KB agg tile
  // total 128 KB -> 1 block/CU, 2 waves/SIMD -> 256-reg budget

  const int bid = blockIdx.x;
  const int l = bid & 7, t = bid >> 3;          // layer <-> XCD affinity
  const int tid = threadIdx.x;
  const int w = tid >> 6, lane = tid & 63, lr = lane & 15, g = lane >> 4;

  const size_t row0 = (size_t)t * BM;
  const u16* lw = wt + (size_t)l * LSTRIDE;
  const float gate = 1.f / (1.f + __expf(-2.f * alpha[l]));
  const float* ewl = ew + l * NN;

  stageDirect(XA, shar_k + ((size_t)l * NN * RPL + row0) * HH, tid);  // K sharer0

  #pragma unroll 1
  for (int path = 0; path < 2; ++path) {
    const float* recvB = (path ? recv_v : recv_k) + ((size_t)l * RPL + row0) * HH;
    const float* sharB = (path ? shar_v : shar_k) + ((size_t)l * NN * RPL + row0) * HH;
    const u16* W1  = lw + (path ? O_AVW1 : O_AKW1);
    const u16* W2  = lw + (path ? O_AVW2 : O_AKW2);
    const u16* FW1 = lw + (path ? O_FVW1 : O_FKW1);
    const u16* FW2 = lw + (path ? O_FVW2 : O_FKW2);
    const float* b1  = (path ? av_b1 : ak_b1) + l * HH;
    const float* b2  = (path ? av_b2 : ak_b2) + l * HH;
    const float* fb1 = (path ? fv_b1 : fk_b1) + l * HH;
    const float* fb2 = (path ? fv_b2 : fk_b2) + l * HH;
    float* outp = out + ((size_t)(path * LL + l) * RPL + row0) * HH;

    // W1 p-slice resident (16 x bf16x8 = 64 regs, read from L2 once/path)
    bf16x8 ws[16];
    {
      const u16* wl = W1 + (w * 32 + lr) * 32 + g * 8;
      #pragma unroll
      for (int kt = 0; kt < 8; ++kt)
        #pragma unroll
        for (int fp = 0; fp < 2; ++fp)
          ws[kt * 2 + fp] = *(const bf16x8*)(wl + kt * 8192 + fp * 512);
    }

    int cur = path;
    float sS = 0.f;

    #pragma unroll 1
    for (int n = 0; n < NN; ++n) {
      float sn = ewl[n] * 0.25f; sS += sn;
      __syncthreads();                         // input n ready in cur buffer
      u16* XC = cur ? XB : XA;
      u16* XO = cur ? XA : XB;
      const float* nsrc = (n < 3) ? sharB + (size_t)(n + 1) * RPL * HH : recvB;
      f32x4 h[2][4]; zero24(h);
      gemm8R<true>(h, ws, XC, nsrc, XO, tid, lr, g);   // W-resident + pinned stage
      if (n == 0) hsUpd<true >(HS, h, b1, sn, w, lr, g);
      else        hsUpd<false>(HS, h, b1, sn, w, lr, g);
      cur ^= 1;
    }
    // after loop: recv in cur buffer, cur^1 dead (last sharer)
    u16* XR = cur ? XB : XA;
    u16* XD = cur ? XA : XB;
    __syncthreads();                           // HS complete; recv staged
    f32x4 agg[2][4]; zero24(agg);
    gemm8S<false>(agg, W2, HS, nullptr, nullptr, tid, w, lr, g);
    epiLds(FB, agg, b2, sS, false, w, lr, g);  // FB = agg + sS*b2
    __syncthreads();                           // FB ready; HS reads done
    f32x4 h2[2][4]; zero24(h2);
    if (path == 0) {
      // fuse GEMM1 (recv half) while streaming V-path sharer0 -> XD
      gemm8S<true>(h2, FW1, XR, shar_v + ((size_t)l * NN * RPL + row0) * HH, XD,
                   tid, w, lr, g);
    } else {
      gemm8S<false>(h2, FW1, XR, nullptr, nullptr, tid, w, lr, g);
    }
    gemm8S<false>(h2, FW1 + 8 * 8192, FB, nullptr, nullptr, tid, w, lr, g);  // agg half
    epiLds(HS, h2, fb1, 1.f, true, w, lr, g);  // HS = fuse hidden (dead since agg)
    __syncthreads();                           // fuse hidden ready
    f32x4 dd[2][4]; zero24(dd);
    gemm8S<false>(dd, FW2, HS, nullptr, nullptr, tid, w, lr, g);
    epiOut(dd, fb2, recvB, outp, gate, w, lr, g);
    // path1 input (V sharer0) sits in XD; after cur^=1 the loop reads it.
    cur ^= 1;
  }
}

extern "C" void kernel_launch(void* const* d_in, const int* in_sizes, int n_in,
                              void* d_out, int out_size, void* d_ws, size_t ws_size,
                              hipStream_t stream)
{
  const float* recv_k = (const float*)d_in[0];
  const float* recv_v = (const float*)d_in[1];
  const float* shar_k = (const float*)d_in[2];
  const float* shar_v = (const float*)d_in[3];
  const float* ew     = (const float*)d_in[4];
  const float* alpha  = (const float*)d_in[5];
  const float* ak_w1 = (const float*)d_in[6];  const float* ak_b1 = (const float*)d_in[7];
  const float* ak_w2 = (const float*)d_in[8];  const float* ak_b2 = (const float*)d_in[9];
  const float* av_w1 = (const float*)d_in[10]; const float* av_b1 = (const float*)d_in[11];
  const float* av_w2 = (const float*)d_in[12]; const float* av_b2 = (const float*)d_in[13];
  const float* fk_w1 = (const float*)d_in[14]; const float* fk_b1 = (const float*)d_in[15];
  const float* fk_w2 = (const float*)d_in[16]; const float* fk_b2 = (const float*)d_in[17];
  const float* fv_w1 = (const float*)d_in[18]; const float* fv_b1 = (const float*)d_in[19];
  const float* fv_w2 = (const float*)d_in[20]; const float* fv_b2 = (const float*)d_in[21];
  u16* wtw = (u16*)d_ws;          // 10485760 B
  float* outp = (float*)d_out;

  prep_wt_k<<<dim3(128, 8, 8), dim3(256), 0, stream>>>(
      ak_w1, ak_w2, av_w1, av_w2, fk_w1, fk_w2, fv_w1, fv_w2, wtw);

  CacheFuser_73873437491748_kernel<<<dim3(1024), dim3(512), 0, stream>>>(
      recv_k, recv_v, shar_k, shar_v, ew, alpha,
      ak_b1, ak_b2, av_b1, av_b2, fk_b1, fk_b2, fv_b1, fv_b2, wtw, outp);
}